// Round 26
// baseline (241.545 us; speedup 1.0000x reference)
//
#include <hip/hip_runtime.h>
#include <hip/hip_bf16.h>
#include <cstddef>

#define BB 4
#define LL 2048
#define DM 256
#define DN 512
#define EE 1024
#define NS 16
#define RK 16
#define NCH 64          // stored scan chunks (32 steps each)
#define SPC 2           // subtiles per chunk
#define CL2 16          // steps per LDS tile
#define NLT (LL / 16)   // l-tiles for xdbl/delta = 128
#define G2C (2 * BB * DN)                       // 4096
#define SZC ((size_t)BB * LL * DN)              // 4,194,304
#define NSZC ((size_t)BB * LL * NS)             // 131,072
#define HSZC ((size_t)NCH * G2C * NS)           // 4,194,304 (bf16 elems)
#define XWSL (48 * 512)                         // 24,576

typedef __attribute__((ext_vector_type(8))) short bf16x8;
typedef __attribute__((ext_vector_type(8))) unsigned short ushort8;
typedef __attribute__((ext_vector_type(4))) unsigned short ushort4v;
typedef __attribute__((ext_vector_type(2))) unsigned short ushort2v;
typedef __attribute__((ext_vector_type(4))) float f32x4;
typedef __attribute__((ext_vector_type(2))) float f32x2;

__device__ __forceinline__ float fsilu(float x) { return x / (1.0f + __expf(-x)); }
__device__ __forceinline__ float fsoftplus_fast(float x) {
  return x > 20.0f ? x : __logf(1.0f + __expf(x));
}
__device__ __forceinline__ unsigned short f2bf(float x) {  // RNE float->bf16
  union { float f; unsigned int u; } v; v.f = x;
  unsigned int r = v.u + 0x7fffu + ((v.u >> 16) & 1u);
  return (unsigned short)(r >> 16);
}
__device__ __forceinline__ float bf2f(unsigned short x) {
  union { unsigned int u; float f; } v; v.u = ((unsigned int)x) << 16;
  return v.f;
}

// ---------------------------------------------------------------------------
// in_proj (both streams). Tile 128e x 64l, grid (32, 8, BB*2).
// ---------------------------------------------------------------------------
__global__ __launch_bounds__(256) void in_proj_mfma(
    const float* __restrict__ h_a, const float* __restrict__ h_v,
    const float* __restrict__ w_a, const float* __restrict__ w_v,
    unsigned short* __restrict__ xz, unsigned short* __restrict__ z_t) {
  __shared__ unsigned short ht[64][40];   // [l][k] bf16
  __shared__ unsigned short wt[128][40];  // [e][k]
  const int bz = blockIdx.z;
  const int b = bz & 3;
  const int str = bz >> 2;
  const float* h = str ? h_v : h_a;
  const float* w = str ? w_v : w_a;
  unsigned short* xzs = xz + (size_t)str * SZC;
  unsigned short* zts = z_t + (size_t)str * SZC;
  const int e0 = blockIdx.y * 128;
  const int l0 = blockIdx.x * 64;
  const int tid = threadIdx.x;
  const int lane = tid & 63;
  const int wv = tid >> 6;
  const bool zblk = (e0 >= DN);
  const int krow = (lane >> 4) * 8;
  const int rlo = lane & 15;
  const int rbase = (lane >> 4) * 4;

  f32x4 acc[8];
#pragma unroll
  for (int i = 0; i < 8; i++) acc[i] = (f32x4){0.f, 0.f, 0.f, 0.f};

  for (int dk = 0; dk < DM; dk += 32) {
    {
      int row = tid >> 2;
      int seg = (tid & 3) * 8;
      const float* hp = h + ((size_t)b * LL + l0 + row) * DM + dk + seg;
      float4 ha = *(const float4*)hp, hb = *(const float4*)(hp + 4);
      ushort8 hv;
      hv[0] = f2bf(ha.x); hv[1] = f2bf(ha.y); hv[2] = f2bf(ha.z); hv[3] = f2bf(ha.w);
      hv[4] = f2bf(hb.x); hv[5] = f2bf(hb.y); hv[6] = f2bf(hb.z); hv[7] = f2bf(hb.w);
      *(ushort8*)&ht[row][seg] = hv;
    }
#pragma unroll
    for (int it = 0; it < 2; it++) {
      int idx = it * 256 + tid;
      int row = idx >> 2;
      int seg = (idx & 3) * 8;
      const float* wp = w + (size_t)(e0 + row) * DM + dk + seg;
      float4 wa = *(const float4*)wp, wb = *(const float4*)(wp + 4);
      ushort8 wv8;
      wv8[0] = f2bf(wa.x); wv8[1] = f2bf(wa.y); wv8[2] = f2bf(wa.z); wv8[3] = f2bf(wa.w);
      wv8[4] = f2bf(wb.x); wv8[5] = f2bf(wb.y); wv8[6] = f2bf(wb.z); wv8[7] = f2bf(wb.w);
      *(ushort8*)&wt[row][seg] = wv8;
    }
    __syncthreads();
    if (!zblk) {
      bf16x8 af0 = *(bf16x8*)&wt[wv * 32 + 0 * 16 + rlo][krow];
      bf16x8 af1 = *(bf16x8*)&wt[wv * 32 + 1 * 16 + rlo][krow];
      bf16x8 bf0 = *(bf16x8*)&ht[0 * 16 + rlo][krow];
      bf16x8 bf1 = *(bf16x8*)&ht[1 * 16 + rlo][krow];
      bf16x8 bf2 = *(bf16x8*)&ht[2 * 16 + rlo][krow];
      bf16x8 bf3 = *(bf16x8*)&ht[3 * 16 + rlo][krow];
      acc[0] = __builtin_amdgcn_mfma_f32_16x16x32_bf16(af0, bf0, acc[0], 0, 0, 0);
      acc[1] = __builtin_amdgcn_mfma_f32_16x16x32_bf16(af0, bf1, acc[1], 0, 0, 0);
      acc[2] = __builtin_amdgcn_mfma_f32_16x16x32_bf16(af0, bf2, acc[2], 0, 0, 0);
      acc[3] = __builtin_amdgcn_mfma_f32_16x16x32_bf16(af0, bf3, acc[3], 0, 0, 0);
      acc[4] = __builtin_amdgcn_mfma_f32_16x16x32_bf16(af1, bf0, acc[4], 0, 0, 0);
      acc[5] = __builtin_amdgcn_mfma_f32_16x16x32_bf16(af1, bf1, acc[5], 0, 0, 0);
      acc[6] = __builtin_amdgcn_mfma_f32_16x16x32_bf16(af1, bf2, acc[6], 0, 0, 0);
      acc[7] = __builtin_amdgcn_mfma_f32_16x16x32_bf16(af1, bf3, acc[7], 0, 0, 0);
    } else {
      bf16x8 af0 = *(bf16x8*)&ht[0 * 16 + rlo][krow];
      bf16x8 af1 = *(bf16x8*)&ht[1 * 16 + rlo][krow];
      bf16x8 af2 = *(bf16x8*)&ht[2 * 16 + rlo][krow];
      bf16x8 af3 = *(bf16x8*)&ht[3 * 16 + rlo][krow];
      bf16x8 bf0 = *(bf16x8*)&wt[wv * 32 + 0 * 16 + rlo][krow];
      bf16x8 bf1 = *(bf16x8*)&wt[wv * 32 + 1 * 16 + rlo][krow];
      acc[0] = __builtin_amdgcn_mfma_f32_16x16x32_bf16(af0, bf0, acc[0], 0, 0, 0);
      acc[1] = __builtin_amdgcn_mfma_f32_16x16x32_bf16(af0, bf1, acc[1], 0, 0, 0);
      acc[2] = __builtin_amdgcn_mfma_f32_16x16x32_bf16(af1, bf0, acc[2], 0, 0, 0);
      acc[3] = __builtin_amdgcn_mfma_f32_16x16x32_bf16(af1, bf1, acc[3], 0, 0, 0);
      acc[4] = __builtin_amdgcn_mfma_f32_16x16x32_bf16(af2, bf0, acc[4], 0, 0, 0);
      acc[5] = __builtin_amdgcn_mfma_f32_16x16x32_bf16(af2, bf1, acc[5], 0, 0, 0);
      acc[6] = __builtin_amdgcn_mfma_f32_16x16x32_bf16(af3, bf0, acc[6], 0, 0, 0);
      acc[7] = __builtin_amdgcn_mfma_f32_16x16x32_bf16(af3, bf1, acc[7], 0, 0, 0);
    }
    __syncthreads();
  }
  if (!zblk) {
#pragma unroll
    for (int m = 0; m < 2; m++)
#pragma unroll
      for (int n = 0; n < 4; n++)
#pragma unroll
        for (int r = 0; r < 4; r++) {
          int e = e0 + wv * 32 + m * 16 + rbase + r;
          int l = l0 + n * 16 + rlo;
          xzs[((size_t)b * DN + e) * LL + l] = f2bf(acc[m * 4 + n][r]);
        }
  } else {
#pragma unroll
    for (int m = 0; m < 4; m++)
#pragma unroll
      for (int n = 0; n < 2; n++)
#pragma unroll
        for (int r = 0; r < 4; r++) {
          int l = l0 + m * 16 + rbase + r;
          int d = (e0 - DN) + wv * 32 + n * 16 + rlo;
          zts[((size_t)b * LL + l) * DN + d] = f2bf(fsilu(acc[m * 2 + n][r]));
        }
  }
}

// ---------------------------------------------------------------------------
// conv (both streams): grid ((LL/32)*4, BB, 4): z = str*2 + rev.
// ---------------------------------------------------------------------------
__global__ __launch_bounds__(256) void conv_kernel(
    const unsigned short* __restrict__ xz,
    const float* __restrict__ cw_af, const float* __restrict__ cb_af,
    const float* __restrict__ cw_ar, const float* __restrict__ cb_ar,
    const float* __restrict__ cw_vf, const float* __restrict__ cb_vf,
    const float* __restrict__ cw_vr, const float* __restrict__ cb_vr,
    unsigned short* __restrict__ u) {
  __shared__ float xt[128][33];
  const int slab = blockIdx.z;      // str*2 + rev
  const int rev = slab & 1;
  const int str = slab >> 1;
  const int b = blockIdx.y;
  const int dc0 = (blockIdx.x & 3) * 128;
  const int l0 = (blockIdx.x >> 2) * 32;
  const int tid = threadIdx.x;
  const int lc = tid & 31;
  const int dg = tid >> 5;
  const int l = l0 + lc;
  const float* conv_w = str ? (rev ? cw_vr : cw_vf) : (rev ? cw_ar : cw_af);
  const float* conv_b = str ? (rev ? cb_vr : cb_vf) : (rev ? cb_ar : cb_af);
  const unsigned short* xzs = xz + (size_t)str * SZC;
  unsigned short* u_out = u + (size_t)slab * SZC;

#pragma unroll
  for (int i = 0; i < 16; i++) {
    int dloc = dg * 16 + i;
    int dd = dc0 + dloc;
    const unsigned short* base = xzs + ((size_t)b * DN + dd) * LL;
    float4 cw4 = *(const float4*)(conv_w + dd * 4);
    float a0 = conv_b[dd];
    if (rev) {
      a0 = fmaf(cw4.w, bf2f(base[l]), a0);
      if (l + 1 < LL) a0 = fmaf(cw4.z, bf2f(base[l + 1]), a0);
      if (l + 2 < LL) a0 = fmaf(cw4.y, bf2f(base[l + 2]), a0);
      if (l + 3 < LL) a0 = fmaf(cw4.x, bf2f(base[l + 3]), a0);
    } else {
      a0 = fmaf(cw4.w, bf2f(base[l]), a0);
      if (l - 1 >= 0) a0 = fmaf(cw4.z, bf2f(base[l - 1]), a0);
      if (l - 2 >= 0) a0 = fmaf(cw4.y, bf2f(base[l - 2]), a0);
      if (l - 3 >= 0) a0 = fmaf(cw4.x, bf2f(base[l - 3]), a0);
    }
    xt[dloc][lc] = fsilu(a0);
  }
  __syncthreads();
#pragma unroll
  for (int j = 0; j < 8; j++) {
    int idx = j * 256 + tid;
    int d2 = idx & 63;
    int l2 = idx >> 6;
    ushort2v v;
    v[0] = f2bf(xt[2 * d2][l2]);
    v[1] = f2bf(xt[2 * d2 + 1][l2]);
    *(ushort2v*)&u_out[((size_t)b * LL + l0 + l2) * DN + dc0 + 2 * d2] = v;
  }
}

// ---------------------------------------------------------------------------
// prep: convert all 4 x_w matrices to bf16 slabs.
// ---------------------------------------------------------------------------
__global__ __launch_bounds__(256) void xw_prep_kernel(
    const float* __restrict__ a_f, const float* __restrict__ a_r,
    const float* __restrict__ v_f, const float* __restrict__ v_r,
    unsigned short* __restrict__ o) {
  int i = blockIdx.x * 256 + threadIdx.x;
  if (i < XWSL) {
    o[i] = f2bf(a_f[i]);
    o[i + XWSL] = f2bf(a_r[i]);
    o[i + 2 * XWSL] = f2bf(v_f[i]);
    o[i + 3 * XWSL] = f2bf(v_r[i]);
  }
}

// ---------------------------------------------------------------------------
// xdbl (both streams): grid (NLT, BB, 4): z = str*2 + rev.
// ---------------------------------------------------------------------------
__global__ __launch_bounds__(256) void xdbl_kernel(
    const unsigned short* __restrict__ u, const unsigned short* __restrict__ xwbf,
    float* __restrict__ dtv_g, float* __restrict__ Bb, float* __restrict__ Cb) {
  __shared__ __align__(16) unsigned short ub[4][16][136];
  __shared__ float red[4][48][17];
  const int slab = blockIdx.z;
  const int b = blockIdx.y;
  const int lt = blockIdx.x;
  const int l0 = lt * 16;
  const int tid = threadIdx.x;
  const int lane = tid & 63;
  const int w = tid >> 6;
  const int rlo = lane & 15;
  const int hi4 = lane >> 4;
  const int kseg = hi4 * 8;

  const unsigned short* up = u + (size_t)slab * SZC + ((size_t)b * LL + l0) * DN;
  const unsigned short* xwb = xwbf + (size_t)slab * XWSL;
  float* B_out = Bb + (size_t)slab * NSZC;
  float* C_out = Cb + (size_t)slab * NSZC;

#pragma unroll
  for (int j = 0; j < 4; j++) {
    int idx = j * 256 + tid;
    int l2 = idx >> 6;
    int c8 = idx & 63;
    ushort8 v = *(const ushort8*)(up + (size_t)l2 * DN + c8 * 8);
    *(ushort8*)&ub[c8 >> 4][l2][(c8 & 15) * 8] = v;
  }
  __syncthreads();

  f32x4 am0 = (f32x4){0.f, 0.f, 0.f, 0.f};
  f32x4 am1 = (f32x4){0.f, 0.f, 0.f, 0.f};
  f32x4 am2 = (f32x4){0.f, 0.f, 0.f, 0.f};
#pragma unroll
  for (int ks = 0; ks < 4; ks++) {
    bf16x8 bfrag = *(bf16x8*)&ub[w][rlo][ks * 32 + kseg];
    const unsigned short* xp = xwb + (size_t)(w * 128 + ks * 32 + kseg);
    bf16x8 a0 = *(const bf16x8*)(xp + (size_t)(0 + rlo) * 512);
    bf16x8 a1 = *(const bf16x8*)(xp + (size_t)(16 + rlo) * 512);
    bf16x8 a2 = *(const bf16x8*)(xp + (size_t)(32 + rlo) * 512);
    am0 = __builtin_amdgcn_mfma_f32_16x16x32_bf16(a0, bfrag, am0, 0, 0, 0);
    am1 = __builtin_amdgcn_mfma_f32_16x16x32_bf16(a1, bfrag, am1, 0, 0, 0);
    am2 = __builtin_amdgcn_mfma_f32_16x16x32_bf16(a2, bfrag, am2, 0, 0, 0);
  }
  {
    const int rbase = hi4 * 4;
#pragma unroll
    for (int r = 0; r < 4; r++) red[w][0 + rbase + r][rlo] = am0[r];
#pragma unroll
    for (int r = 0; r < 4; r++) red[w][16 + rbase + r][rlo] = am1[r];
#pragma unroll
    for (int r = 0; r < 4; r++) red[w][32 + rbase + r][rlo] = am2[r];
  }
  __syncthreads();
  float* dtvp = dtv_g + (((size_t)slab * BB + b) * NLT + lt) * 256;
#pragma unroll
  for (int i = 0; i < 3; i++) {
    int o = i * 256 + tid;
    int row = o >> 4, col = o & 15;
    float s = (red[0][row][col] + red[1][row][col]) +
              (red[2][row][col] + red[3][row][col]);
    if (row < 16)
      dtvp[(size_t)row * 16 + col] = s;
    else if (row < 32)
      B_out[((size_t)b * LL + l0 + col) * NS + (row - 16)] = s;
    else
      C_out[((size_t)b * LL + l0 + col) * NS + (row - 32)] = s;
  }
}

// ---------------------------------------------------------------------------
// delta (both streams): dtv transposed in LDS; dl output BF16.
// ---------------------------------------------------------------------------
__global__ __launch_bounds__(256) void delta_kernel(
    const float* __restrict__ dtv_g,
    const float* __restrict__ dtw_af, const float* __restrict__ dtb_af,
    const float* __restrict__ dtw_ar, const float* __restrict__ dtb_ar,
    const float* __restrict__ dtw_vf, const float* __restrict__ dtb_vf,
    const float* __restrict__ dtw_vr, const float* __restrict__ dtb_vr,
    unsigned short* __restrict__ dl) {
  __shared__ __align__(16) float dtvT[16][20];
  const int slab = blockIdx.z;
  const int rev = slab & 1;
  const int str = slab >> 1;
  const int b = blockIdx.y;
  const int lt = blockIdx.x;
  const int l0 = lt * 16;
  const int tid = threadIdx.x;
  const float* dt_w = str ? (rev ? dtw_vr : dtw_vf) : (rev ? dtw_ar : dtw_af);
  const float* dt_b = str ? (rev ? dtb_vr : dtb_vf) : (rev ? dtb_ar : dtb_af);
  unsigned short* dl_out = dl + (size_t)slab * SZC;

  {
    const float* dtvp = dtv_g + (((size_t)slab * BB + b) * NLT + lt) * 256;
    float v = dtvp[tid];  // tid = k*16 + l
    dtvT[tid & 15][tid >> 4] = v;
  }
  __syncthreads();

  const int dd0 = tid, dd1 = tid + 256;
  const float4* wr0 = (const float4*)(dt_w + (size_t)dd0 * RK);
  const float4* wr1 = (const float4*)(dt_w + (size_t)dd1 * RK);
  float4 a_0 = wr0[0], a_1 = wr0[1], a_2 = wr0[2], a_3 = wr0[3];
  float4 b_0 = wr1[0], b_1 = wr1[1], b_2 = wr1[2], b_3 = wr1[3];
  float bias0 = dt_b[dd0], bias1 = dt_b[dd1];

#pragma unroll
  for (int l2 = 0; l2 < 16; l2++) {
    float4 q0 = *(const float4*)&dtvT[l2][0];
    float4 q1 = *(const float4*)&dtvT[l2][4];
    float4 q2 = *(const float4*)&dtvT[l2][8];
    float4 q3 = *(const float4*)&dtvT[l2][12];
    float s0 = bias0, s1 = bias1;
    s0 = fmaf(a_0.x, q0.x, s0); s1 = fmaf(b_0.x, q0.x, s1);
    s0 = fmaf(a_0.y, q0.y, s0); s1 = fmaf(b_0.y, q0.y, s1);
    s0 = fmaf(a_0.z, q0.z, s0); s1 = fmaf(b_0.z, q0.z, s1);
    s0 = fmaf(a_0.w, q0.w, s0); s1 = fmaf(b_0.w, q0.w, s1);
    s0 = fmaf(a_1.x, q1.x, s0); s1 = fmaf(b_1.x, q1.x, s1);
    s0 = fmaf(a_1.y, q1.y, s0); s1 = fmaf(b_1.y, q1.y, s1);
    s0 = fmaf(a_1.z, q1.z, s0); s1 = fmaf(b_1.z, q1.z, s1);
    s0 = fmaf(a_1.w, q1.w, s0); s1 = fmaf(b_1.w, q1.w, s1);
    s0 = fmaf(a_2.x, q2.x, s0); s1 = fmaf(b_2.x, q2.x, s1);
    s0 = fmaf(a_2.y, q2.y, s0); s1 = fmaf(b_2.y, q2.y, s1);
    s0 = fmaf(a_2.z, q2.z, s0); s1 = fmaf(b_2.z, q2.z, s1);
    s0 = fmaf(a_2.w, q2.w, s0); s1 = fmaf(b_2.w, q2.w, s1);
    s0 = fmaf(a_3.x, q3.x, s0); s1 = fmaf(b_3.x, q3.x, s1);
    s0 = fmaf(a_3.y, q3.y, s0); s1 = fmaf(b_3.y, q3.y, s1);
    s0 = fmaf(a_3.z, q3.z, s0); s1 = fmaf(b_3.z, q3.z, s1);
    s0 = fmaf(a_3.w, q3.w, s0); s1 = fmaf(b_3.w, q3.w, s1);
    unsigned short* rowp = dl_out + ((size_t)b * LL + l0 + l2) * DN;
    rowp[dd0] = f2bf(fsoftplus_fast(s0));
    rowp[dd1] = f2bf(fsoftplus_fast(s1));
  }
}

// ---------------------------------------------------------------------------
// Scan (both streams). Stored chunk = 32 steps = 2 LDS subtiles of 16,
// restaged between subtiles with plain barriers (no prefetch regs). Grid
// (NCH*16, 2) = 2048 blocks = full co-residency at 8/CU. Halves hend/combine
// traffic vs 128-chunk version. h crosses subtile boundary in registers.
// ---------------------------------------------------------------------------
template <int PHASE>
__global__ __launch_bounds__(256) void scan_kernel(
    unsigned short* __restrict__ u, const unsigned short* __restrict__ dl,
    const unsigned short* __restrict__ z_t, const float* __restrict__ Bb,
    const float* __restrict__ Cb, const float* __restrict__ A_log,
    const float* __restrict__ Ab_log,
    const float* __restrict__ D_af, const float* __restrict__ D_ar,
    const float* __restrict__ D_vf, const float* __restrict__ D_vr,
    unsigned short* __restrict__ hend, float* __restrict__ sumdl) {
  __shared__ unsigned short us[CL2][256];   // 8 KB
  __shared__ unsigned short dls[CL2][256];  // 8 KB
  __shared__ __align__(16) float Bs[CL2][16];
  __shared__ __align__(16) float Cs[CL2][16];
  const int tid = threadIdx.x;
  const int str = blockIdx.y;
  const int ch0 = (blockIdx.x & 15) * 256;
  const int chunk = blockIdx.x >> 4;  // 0..NCH-1
  const int ch = ch0 + tid;
  const bool rev = ch0 >= BB * DN;
  const int slab = str * 2 + (rev ? 1 : 0);
  const int cid0 = rev ? ch0 - BB * DN : ch0;
  const int b = cid0 >> 9;
  const int d0 = cid0 & (DN - 1);
  const int d = d0 + tid;
  const int lane = tid & 63;
  const int w = tid >> 6;

  const float* Arow = (rev ? Ab_log : A_log) + d * NS;
  float Av[NS];
#pragma unroll
  for (int n = 0; n < NS; n++) Av[n] = -__expf(Arow[n]);
  bool fastA = true;
#pragma unroll
  for (int n = 0; n < NS; n++)
    if (fabsf(Av[n] + (float)(n + 1)) > 1e-4f * (float)(n + 1)) fastA = false;
  const float* Dsel = str ? (rev ? D_vr : D_vf) : (rev ? D_ar : D_af);
  const float Dd = Dsel[d];

  unsigned short* ub0 = u + (size_t)slab * SZC + (size_t)b * LL * DN + d0;
  const unsigned short* db0 = dl + (size_t)slab * SZC + (size_t)b * LL * DN + d0;
  const unsigned short* zb0 = z_t + (size_t)str * SZC + (size_t)b * LL * DN + d0;
  const float* Bp0 = Bb + (size_t)slab * NSZC + (size_t)b * LL * NS;
  const float* Cp0 = Cb + (size_t)slab * NSZC + (size_t)b * LL * NS;
  unsigned short* hendp = hend + (size_t)str * HSZC;
  float* sumdlp = sumdl + (size_t)str * NCH * G2C;

  auto stage = [&](int tlo) {
#pragma unroll
    for (int j4 = 0; j4 < 4; j4++) {
      int row = w * 4 + j4;
      ushort4v uu = *(const ushort4v*)(ub0 + (size_t)(tlo + row) * DN + lane * 4);
      *(ushort4v*)&us[row][lane * 4] = uu;
      ushort4v dd4 = *(const ushort4v*)(db0 + (size_t)(tlo + row) * DN + lane * 4);
      *(ushort4v*)&dls[row][lane * 4] = dd4;
    }
    Bs[tid >> 4][tid & 15] = Bp0[(size_t)(tlo + (tid >> 4)) * NS + (tid & 15)];
    if (PHASE == 3)
      Cs[tid >> 4][tid & 15] = Cp0[(size_t)(tlo + (tid >> 4)) * NS + (tid & 15)];
  };

  float h[NS];
  if (PHASE == 3) {
    const unsigned short* hp = hendp + ((size_t)chunk * G2C + ch) * NS;
#pragma unroll
    for (int n = 0; n < NS; n++) h[n] = bf2f(hp[n]);
  } else {
#pragma unroll
    for (int n = 0; n < NS; n++) h[n] = 0.f;
  }
  float sdl = 0.f;
  f32x2 h2[8];
  if (fastA) {
#pragma unroll
    for (int k = 0; k < 8; k++) h2[k] = (f32x2){h[2 * k], h[2 * k + 1]};
  }

  // subtile time origins: fwd s -> chunk*32 + s*16 ; rev s -> LL-32*chunk-16*(s+1)
#pragma unroll
  for (int s = 0; s < SPC; s++) {
    const int tlo = rev ? (LL - 32 * chunk - 16 * (s + 1)) : (32 * chunk + 16 * s);
    if (s > 0) __syncthreads();  // previous subtile's readers done
    stage(tlo);
    __syncthreads();

    unsigned short* uyb = ub0 + (size_t)tlo * DN;
    const unsigned short* zb = zb0 + (size_t)tlo * DN;

    if (fastA) {
#pragma unroll
      for (int jj = 0; jj < CL2; jj++) {
        const int j = rev ? (CL2 - 1 - jj) : jj;
        const float uc = bf2f(us[j][tid]);
        const float dc = bf2f(dls[j][tid]);
        const f32x2* B2 = (const f32x2*)&Bs[j][0];
        const f32x2* C2 = (const f32x2*)&Cs[j][0];
        const float dlu = dc * uc;
        const f32x2 dlu2 = (f32x2){dlu, dlu};
        const float p1 = __expf(-dc);
        const float p2 = p1 * p1;
        const f32x2 p22 = (f32x2){p2, p2};
        f32x2 P[8];
        P[0] = (f32x2){p1, p2};
#pragma unroll
        for (int k = 1; k < 8; k++) P[k] = P[k - 1] * p22;
        f32x2 acc2 = (f32x2){0.f, 0.f};
#pragma unroll
        for (int k = 0; k < 8; k++) {
          f32x2 db2 = dlu2 * B2[k];
          h2[k] = __builtin_elementwise_fma(P[k], h2[k], db2);
          if (PHASE == 3) acc2 = __builtin_elementwise_fma(h2[k], C2[k], acc2);
        }
        if (PHASE == 1) sdl += dc;
        if (PHASE == 3) {
          const float zc = bf2f(zb[(size_t)j * DN + tid]);
          float y = fmaf(uc, Dd, acc2.x + acc2.y) * zc;
          uyb[(size_t)j * DN + tid] = f2bf(y);
        }
      }
    } else {
#pragma unroll
      for (int jj = 0; jj < CL2; jj++) {
        const int j = rev ? (CL2 - 1 - jj) : jj;
        const float uc = bf2f(us[j][tid]);
        const float dc = bf2f(dls[j][tid]);
        const float dlu = dc * uc;
        float acc = 0.f;
#pragma unroll
        for (int n = 0; n < NS; n++) {
          h[n] = fmaf(__expf(dc * Av[n]), h[n], dlu * Bs[j][n]);
          if (PHASE == 3) acc = fmaf(h[n], Cs[j][n], acc);
        }
        if (PHASE == 1) sdl += dc;
        if (PHASE == 3) {
          const float zc = bf2f(zb[(size_t)j * DN + tid]);
          float y = fmaf(uc, Dd, acc) * zc;
          uyb[(size_t)j * DN + tid] = f2bf(y);
        }
      }
    }
  }

  if (PHASE == 1) {
    if (fastA) {
#pragma unroll
      for (int k = 0; k < 8; k++) { h[2 * k] = h2[k].x; h[2 * k + 1] = h2[k].y; }
    }
    unsigned short* hp = hendp + ((size_t)chunk * G2C + ch) * NS;
#pragma unroll
    for (int n = 0; n < NS; n++) hp[n] = f2bf(h[n]);
    sumdlp[(size_t)chunk * G2C + ch] = sdl;
  }
}

// ---------------------------------------------------------------------------
// Phase 2 (both streams): grid (G2C/16, 2). NCH chunks now.
// ---------------------------------------------------------------------------
__global__ __launch_bounds__(256) void scan_combine_kernel(
    const float* __restrict__ A_log, const float* __restrict__ Ab_log,
    unsigned short* __restrict__ hend, const float* __restrict__ sumdl) {
  __shared__ float tile[8][256];
  __shared__ float sd[8][16];
  const int tid = threadIdx.x;
  const int str = blockIdx.y;
  const int ch0 = blockIdx.x * 16;
  const int chl = tid >> 4;
  const int n = tid & 15;
  const int ch = ch0 + chl;
  const bool rev = ch >= BB * DN;
  const int d = ch & (DN - 1);
  const float Av = -__expf((rev ? Ab_log : A_log)[d * NS + n]);
  unsigned short* hendp = hend + (size_t)str * HSZC;
  const float* sumdlp = sumdl + (size_t)str * NCH * G2C;
  float H = 0.f;
  for (int cb = 0; cb < NCH / 8; cb++) {
#pragma unroll
    for (int j = 0; j < 8; j++)
      tile[j][tid] = bf2f(hendp[((size_t)(cb * 8 + j) * G2C + ch0) * NS + tid]);
    if (tid < 128) {
      int j = tid >> 4, k = tid & 15;
      sd[j][k] = sumdlp[(size_t)(cb * 8 + j) * G2C + ch0 + k];
    }
    __syncthreads();
#pragma unroll
    for (int j = 0; j < 8; j++) {
      float tmp = tile[j][tid];
      tile[j][tid] = H;
      H = fmaf(__expf(Av * sd[j][chl]), H, tmp);
    }
    __syncthreads();
#pragma unroll
    for (int j = 0; j < 8; j++)
      hendp[((size_t)(cb * 8 + j) * G2C + ch0) * NS + tid] = f2bf(tile[j][tid]);
    __syncthreads();
  }
}

// ---------------------------------------------------------------------------
// out_proj (both streams): grid (32, 4, BB*2).
// ---------------------------------------------------------------------------
__global__ __launch_bounds__(256) void out_proj_mfma(
    const unsigned short* __restrict__ u,
    const float* __restrict__ ow_a, const float* __restrict__ ow_v,
    float* __restrict__ outp) {
  __shared__ unsigned short yt[64][40];
  __shared__ unsigned short wo[64][40];
  const int bz = blockIdx.z;
  const int b = bz & 3;
  const int str = bz >> 2;
  const float* ow = str ? ow_v : ow_a;
  const unsigned short* yf = u + (size_t)(str * 2) * SZC;
  const unsigned short* yr = u + (size_t)(str * 2 + 1) * SZC;
  float* outs = outp + (size_t)str * BB * LL * DM;
  const int m0 = blockIdx.y * 64;
  const int l0 = blockIdx.x * 64;
  const int tid = threadIdx.x;
  const int lane = tid & 63;
  const int wid = tid >> 6;
  const int wm = wid >> 1, wn = wid & 1;
  const int krow = (lane >> 4) * 8;
  const int rlo = lane & 15;

  f32x4 acc[2][2];
#pragma unroll
  for (int i = 0; i < 2; i++)
#pragma unroll
    for (int j = 0; j < 2; j++) acc[i][j] = (f32x4){0.f, 0.f, 0.f, 0.f};

  for (int dk = 0; dk < DN; dk += 32) {
    {
      int row = tid >> 2;
      int seg = (tid & 3) * 8;
      ushort8 a = *(const ushort8*)(yf + ((size_t)b * LL + l0 + row) * DN + dk + seg);
      ushort8 c = *(const ushort8*)(yr + ((size_t)b * LL + l0 + row) * DN + dk + seg);
      ushort8 yv;
#pragma unroll
      for (int k = 0; k < 8; k++) yv[k] = f2bf(0.5f * (bf2f(a[k]) + bf2f(c[k])));
      *(ushort8*)&yt[row][seg] = yv;
      const float* wp = ow + (size_t)(m0 + row) * DN + dk + seg;
      float4 w0 = *(const float4*)wp, w1 = *(const float4*)(wp + 4);
      ushort8 wv;
      wv[0] = f2bf(w0.x); wv[1] = f2bf(w0.y); wv[2] = f2bf(w0.z); wv[3] = f2bf(w0.w);
      wv[4] = f2bf(w1.x); wv[5] = f2bf(w1.y); wv[6] = f2bf(w1.z); wv[7] = f2bf(w1.w);
      *(ushort8*)&wo[row][seg] = wv;
    }
    __syncthreads();
    bf16x8 a0 = *(bf16x8*)&yt[wm * 32 + rlo][krow];
    bf16x8 a1 = *(bf16x8*)&yt[wm * 32 + 16 + rlo][krow];
    bf16x8 b0 = *(bf16x8*)&wo[wn * 32 + rlo][krow];
    bf16x8 b1 = *(bf16x8*)&wo[wn * 32 + 16 + rlo][krow];
    acc[0][0] = __builtin_amdgcn_mfma_f32_16x16x32_bf16(a0, b0, acc[0][0], 0, 0, 0);
    acc[0][1] = __builtin_amdgcn_mfma_f32_16x16x32_bf16(a0, b1, acc[0][1], 0, 0, 0);
    acc[1][0] = __builtin_amdgcn_mfma_f32_16x16x32_bf16(a1, b0, acc[1][0], 0, 0, 0);
    acc[1][1] = __builtin_amdgcn_mfma_f32_16x16x32_bf16(a1, b1, acc[1][1], 0, 0, 0);
    __syncthreads();
  }
#pragma unroll
  for (int mt = 0; mt < 2; mt++)
#pragma unroll
    for (int nt = 0; nt < 2; nt++)
#pragma unroll
      for (int r = 0; r < 4; r++) {
        int l = l0 + wm * 32 + mt * 16 + (lane >> 4) * 4 + r;
        int m = m0 + wn * 32 + nt * 16 + rlo;
        outs[((size_t)b * LL + l) * DM + m] = acc[mt][nt][r];
      }
}

// ---------------------------------------------------------------------------
extern "C" void kernel_launch(void* const* d_in, const int* in_sizes, int n_in,
                              void* d_out, int out_size, void* d_ws, size_t ws_size,
                              hipStream_t stream) {
  (void)in_sizes; (void)n_in; (void)out_size; (void)ws_size;
  const float* A_log = (const float*)d_in[2];
  const float* Ab_log = (const float*)d_in[3];
  const float* h_a = (const float*)d_in[0];
  const float* h_v = (const float*)d_in[1];
#define AP(i) ((const float*)d_in[4 + (i)])
#define VP(i) ((const float*)d_in[18 + (i)])

  float* ws = (float*)d_ws;
  float* Bb = ws;                                   // 4*NSZC fp32
  float* Cb = Bb + 4 * NSZC;                        // 4*NSZC
  float* sumdl = Cb + 4 * NSZC;                     // 2*NCH*G2C
  float* dtv_g = sumdl + (size_t)2 * NCH * G2C;     // 4*BB*NLT*256
  unsigned short* xwbf = (unsigned short*)(dtv_g + (size_t)4 * BB * NLT * 256);
  unsigned short* z_t = xwbf + 4 * XWSL;            // 2*SZC bf16
  unsigned short* u = z_t + 2 * SZC;                // 4*SZC bf16
  unsigned short* xz = u + 4 * SZC;                 // 2*SZC bf16
  unsigned short* hend = xz + 2 * SZC;              // 2*HSZC bf16
  unsigned short* dl = hend + 2 * HSZC;             // 4*SZC bf16

  hipLaunchKernelGGL(in_proj_mfma, dim3(LL / 64, EE / 128, BB * 2), dim3(256), 0,
                     stream, h_a, h_v, AP(0), VP(0), xz, z_t);
  hipLaunchKernelGGL(xw_prep_kernel, dim3(96), dim3(256), 0, stream,
                     AP(3), AP(9), VP(3), VP(9), xwbf);
  hipLaunchKernelGGL(conv_kernel, dim3((LL / 32) * 4, BB, 4), dim3(256), 0, stream,
                     xz, AP(1), AP(2), AP(7), AP(8), VP(1), VP(2), VP(7), VP(8), u);
  hipLaunchKernelGGL(xdbl_kernel, dim3(NLT, BB, 4), dim3(256), 0, stream,
                     u, xwbf, dtv_g, Bb, Cb);
  hipLaunchKernelGGL(delta_kernel, dim3(NLT, BB, 4), dim3(256), 0, stream,
                     dtv_g, AP(4), AP(5), AP(10), AP(11), VP(4), VP(5), VP(10),
                     VP(11), dl);
  hipLaunchKernelGGL(HIP_KERNEL_NAME(scan_kernel<1>), dim3(NCH * 16, 2), dim3(256),
                     0, stream, u, dl, z_t, Bb, Cb, A_log, Ab_log, AP(6), AP(12),
                     VP(6), VP(12), hend, sumdl);
  hipLaunchKernelGGL(scan_combine_kernel, dim3(G2C / 16, 2), dim3(256), 0, stream,
                     A_log, Ab_log, hend, sumdl);
  hipLaunchKernelGGL(HIP_KERNEL_NAME(scan_kernel<3>), dim3(NCH * 16, 2), dim3(256),
                     0, stream, u, dl, z_t, Bb, Cb, A_log, Ab_log, AP(6), AP(12),
                     VP(6), VP(12), hend, sumdl);
  hipLaunchKernelGGL(out_proj_mfma, dim3(LL / 64, DM / 64, BB * 2), dim3(256), 0,
                     stream, u, AP(13), VP(13), (float*)d_out);
#undef AP
#undef VP
}

// Round 27
// 219.470 us; speedup vs baseline: 1.1006x; 1.1006x over previous
//
#include <hip/hip_runtime.h>
#include <hip/hip_bf16.h>
#include <cstddef>

#define BB 4
#define LL 2048
#define DM 256
#define DN 512
#define EE 1024
#define NS 16
#define RK 16
#define NC2 128         // scan chunks
#define CL2 (LL / NC2)  // chunk length = 16
#define NLT (LL / 16)   // l-tiles for xdbl/delta = 128
#define G2C (2 * BB * DN)                       // 4096
#define SZC ((size_t)BB * LL * DN)              // 4,194,304
#define NSZC ((size_t)BB * LL * NS)             // 131,072
#define HSZC ((size_t)NC2 * G2C * NS)           // 8,388,608 (bf16 elems)
#define XWSL (48 * 512)                         // 24,576

typedef __attribute__((ext_vector_type(8))) short bf16x8;
typedef __attribute__((ext_vector_type(8))) unsigned short ushort8;
typedef __attribute__((ext_vector_type(4))) unsigned short ushort4v;
typedef __attribute__((ext_vector_type(2))) unsigned short ushort2v;
typedef __attribute__((ext_vector_type(4))) float f32x4;
typedef __attribute__((ext_vector_type(2))) float f32x2;

__device__ __forceinline__ float fsilu(float x) { return x / (1.0f + __expf(-x)); }
__device__ __forceinline__ float fsoftplus_fast(float x) {
  return x > 20.0f ? x : __logf(1.0f + __expf(x));
}
__device__ __forceinline__ unsigned short f2bf(float x) {  // RNE float->bf16
  union { float f; unsigned int u; } v; v.f = x;
  unsigned int r = v.u + 0x7fffu + ((v.u >> 16) & 1u);
  return (unsigned short)(r >> 16);
}
__device__ __forceinline__ float bf2f(unsigned short x) {
  union { unsigned int u; float f; } v; v.u = ((unsigned int)x) << 16;
  return v.f;
}

// ---------------------------------------------------------------------------
// in_proj (both streams). Tile 128e x 64l, grid (32, 8, BB*2).
// ---------------------------------------------------------------------------
__global__ __launch_bounds__(256) void in_proj_mfma(
    const float* __restrict__ h_a, const float* __restrict__ h_v,
    const float* __restrict__ w_a, const float* __restrict__ w_v,
    unsigned short* __restrict__ xz, unsigned short* __restrict__ z_t) {
  __shared__ unsigned short ht[64][40];   // [l][k] bf16
  __shared__ unsigned short wt[128][40];  // [e][k]
  const int bz = blockIdx.z;
  const int b = bz & 3;
  const int str = bz >> 2;
  const float* h = str ? h_v : h_a;
  const float* w = str ? w_v : w_a;
  unsigned short* xzs = xz + (size_t)str * SZC;
  unsigned short* zts = z_t + (size_t)str * SZC;
  const int e0 = blockIdx.y * 128;
  const int l0 = blockIdx.x * 64;
  const int tid = threadIdx.x;
  const int lane = tid & 63;
  const int wv = tid >> 6;
  const bool zblk = (e0 >= DN);
  const int krow = (lane >> 4) * 8;
  const int rlo = lane & 15;
  const int rbase = (lane >> 4) * 4;

  f32x4 acc[8];
#pragma unroll
  for (int i = 0; i < 8; i++) acc[i] = (f32x4){0.f, 0.f, 0.f, 0.f};

  for (int dk = 0; dk < DM; dk += 32) {
    {
      int row = tid >> 2;
      int seg = (tid & 3) * 8;
      const float* hp = h + ((size_t)b * LL + l0 + row) * DM + dk + seg;
      float4 ha = *(const float4*)hp, hb = *(const float4*)(hp + 4);
      ushort8 hv;
      hv[0] = f2bf(ha.x); hv[1] = f2bf(ha.y); hv[2] = f2bf(ha.z); hv[3] = f2bf(ha.w);
      hv[4] = f2bf(hb.x); hv[5] = f2bf(hb.y); hv[6] = f2bf(hb.z); hv[7] = f2bf(hb.w);
      *(ushort8*)&ht[row][seg] = hv;
    }
#pragma unroll
    for (int it = 0; it < 2; it++) {
      int idx = it * 256 + tid;
      int row = idx >> 2;
      int seg = (idx & 3) * 8;
      const float* wp = w + (size_t)(e0 + row) * DM + dk + seg;
      float4 wa = *(const float4*)wp, wb = *(const float4*)(wp + 4);
      ushort8 wv8;
      wv8[0] = f2bf(wa.x); wv8[1] = f2bf(wa.y); wv8[2] = f2bf(wa.z); wv8[3] = f2bf(wa.w);
      wv8[4] = f2bf(wb.x); wv8[5] = f2bf(wb.y); wv8[6] = f2bf(wb.z); wv8[7] = f2bf(wb.w);
      *(ushort8*)&wt[row][seg] = wv8;
    }
    __syncthreads();
    if (!zblk) {
      bf16x8 af0 = *(bf16x8*)&wt[wv * 32 + 0 * 16 + rlo][krow];
      bf16x8 af1 = *(bf16x8*)&wt[wv * 32 + 1 * 16 + rlo][krow];
      bf16x8 bf0 = *(bf16x8*)&ht[0 * 16 + rlo][krow];
      bf16x8 bf1 = *(bf16x8*)&ht[1 * 16 + rlo][krow];
      bf16x8 bf2 = *(bf16x8*)&ht[2 * 16 + rlo][krow];
      bf16x8 bf3 = *(bf16x8*)&ht[3 * 16 + rlo][krow];
      acc[0] = __builtin_amdgcn_mfma_f32_16x16x32_bf16(af0, bf0, acc[0], 0, 0, 0);
      acc[1] = __builtin_amdgcn_mfma_f32_16x16x32_bf16(af0, bf1, acc[1], 0, 0, 0);
      acc[2] = __builtin_amdgcn_mfma_f32_16x16x32_bf16(af0, bf2, acc[2], 0, 0, 0);
      acc[3] = __builtin_amdgcn_mfma_f32_16x16x32_bf16(af0, bf3, acc[3], 0, 0, 0);
      acc[4] = __builtin_amdgcn_mfma_f32_16x16x32_bf16(af1, bf0, acc[4], 0, 0, 0);
      acc[5] = __builtin_amdgcn_mfma_f32_16x16x32_bf16(af1, bf1, acc[5], 0, 0, 0);
      acc[6] = __builtin_amdgcn_mfma_f32_16x16x32_bf16(af1, bf2, acc[6], 0, 0, 0);
      acc[7] = __builtin_amdgcn_mfma_f32_16x16x32_bf16(af1, bf3, acc[7], 0, 0, 0);
    } else {
      bf16x8 af0 = *(bf16x8*)&ht[0 * 16 + rlo][krow];
      bf16x8 af1 = *(bf16x8*)&ht[1 * 16 + rlo][krow];
      bf16x8 af2 = *(bf16x8*)&ht[2 * 16 + rlo][krow];
      bf16x8 af3 = *(bf16x8*)&ht[3 * 16 + rlo][krow];
      bf16x8 bf0 = *(bf16x8*)&wt[wv * 32 + 0 * 16 + rlo][krow];
      bf16x8 bf1 = *(bf16x8*)&wt[wv * 32 + 1 * 16 + rlo][krow];
      acc[0] = __builtin_amdgcn_mfma_f32_16x16x32_bf16(af0, bf0, acc[0], 0, 0, 0);
      acc[1] = __builtin_amdgcn_mfma_f32_16x16x32_bf16(af0, bf1, acc[1], 0, 0, 0);
      acc[2] = __builtin_amdgcn_mfma_f32_16x16x32_bf16(af1, bf0, acc[2], 0, 0, 0);
      acc[3] = __builtin_amdgcn_mfma_f32_16x16x32_bf16(af1, bf1, acc[3], 0, 0, 0);
      acc[4] = __builtin_amdgcn_mfma_f32_16x16x32_bf16(af2, bf0, acc[4], 0, 0, 0);
      acc[5] = __builtin_amdgcn_mfma_f32_16x16x32_bf16(af2, bf1, acc[5], 0, 0, 0);
      acc[6] = __builtin_amdgcn_mfma_f32_16x16x32_bf16(af3, bf0, acc[6], 0, 0, 0);
      acc[7] = __builtin_amdgcn_mfma_f32_16x16x32_bf16(af3, bf1, acc[7], 0, 0, 0);
    }
    __syncthreads();
  }
  if (!zblk) {
#pragma unroll
    for (int m = 0; m < 2; m++)
#pragma unroll
      for (int n = 0; n < 4; n++)
#pragma unroll
        for (int r = 0; r < 4; r++) {
          int e = e0 + wv * 32 + m * 16 + rbase + r;
          int l = l0 + n * 16 + rlo;
          xzs[((size_t)b * DN + e) * LL + l] = f2bf(acc[m * 4 + n][r]);
        }
  } else {
#pragma unroll
    for (int m = 0; m < 4; m++)
#pragma unroll
      for (int n = 0; n < 2; n++)
#pragma unroll
        for (int r = 0; r < 4; r++) {
          int l = l0 + m * 16 + rbase + r;
          int d = (e0 - DN) + wv * 32 + n * 16 + rlo;
          zts[((size_t)b * LL + l) * DN + d] = f2bf(fsilu(acc[m * 2 + n][r]));
        }
  }
}

// ---------------------------------------------------------------------------
// conv (both streams): grid ((LL/32)*4, BB, 4): z = str*2 + rev.
// ---------------------------------------------------------------------------
__global__ __launch_bounds__(256) void conv_kernel(
    const unsigned short* __restrict__ xz,
    const float* __restrict__ cw_af, const float* __restrict__ cb_af,
    const float* __restrict__ cw_ar, const float* __restrict__ cb_ar,
    const float* __restrict__ cw_vf, const float* __restrict__ cb_vf,
    const float* __restrict__ cw_vr, const float* __restrict__ cb_vr,
    unsigned short* __restrict__ u) {
  __shared__ float xt[128][33];
  const int slab = blockIdx.z;      // str*2 + rev
  const int rev = slab & 1;
  const int str = slab >> 1;
  const int b = blockIdx.y;
  const int dc0 = (blockIdx.x & 3) * 128;
  const int l0 = (blockIdx.x >> 2) * 32;
  const int tid = threadIdx.x;
  const int lc = tid & 31;
  const int dg = tid >> 5;
  const int l = l0 + lc;
  const float* conv_w = str ? (rev ? cw_vr : cw_vf) : (rev ? cw_ar : cw_af);
  const float* conv_b = str ? (rev ? cb_vr : cb_vf) : (rev ? cb_ar : cb_af);
  const unsigned short* xzs = xz + (size_t)str * SZC;
  unsigned short* u_out = u + (size_t)slab * SZC;

#pragma unroll
  for (int i = 0; i < 16; i++) {
    int dloc = dg * 16 + i;
    int dd = dc0 + dloc;
    const unsigned short* base = xzs + ((size_t)b * DN + dd) * LL;
    float4 cw4 = *(const float4*)(conv_w + dd * 4);
    float a0 = conv_b[dd];
    if (rev) {
      a0 = fmaf(cw4.w, bf2f(base[l]), a0);
      if (l + 1 < LL) a0 = fmaf(cw4.z, bf2f(base[l + 1]), a0);
      if (l + 2 < LL) a0 = fmaf(cw4.y, bf2f(base[l + 2]), a0);
      if (l + 3 < LL) a0 = fmaf(cw4.x, bf2f(base[l + 3]), a0);
    } else {
      a0 = fmaf(cw4.w, bf2f(base[l]), a0);
      if (l - 1 >= 0) a0 = fmaf(cw4.z, bf2f(base[l - 1]), a0);
      if (l - 2 >= 0) a0 = fmaf(cw4.y, bf2f(base[l - 2]), a0);
      if (l - 3 >= 0) a0 = fmaf(cw4.x, bf2f(base[l - 3]), a0);
    }
    xt[dloc][lc] = fsilu(a0);
  }
  __syncthreads();
#pragma unroll
  for (int j = 0; j < 8; j++) {
    int idx = j * 256 + tid;
    int d2 = idx & 63;
    int l2 = idx >> 6;
    ushort2v v;
    v[0] = f2bf(xt[2 * d2][l2]);
    v[1] = f2bf(xt[2 * d2 + 1][l2]);
    *(ushort2v*)&u_out[((size_t)b * LL + l0 + l2) * DN + dc0 + 2 * d2] = v;
  }
}

// ---------------------------------------------------------------------------
// prep: convert all 4 x_w matrices to bf16 slabs.
// ---------------------------------------------------------------------------
__global__ __launch_bounds__(256) void xw_prep_kernel(
    const float* __restrict__ a_f, const float* __restrict__ a_r,
    const float* __restrict__ v_f, const float* __restrict__ v_r,
    unsigned short* __restrict__ o) {
  int i = blockIdx.x * 256 + threadIdx.x;
  if (i < XWSL) {
    o[i] = f2bf(a_f[i]);
    o[i + XWSL] = f2bf(a_r[i]);
    o[i + 2 * XWSL] = f2bf(v_f[i]);
    o[i + 3 * XWSL] = f2bf(v_r[i]);
  }
}

// ---------------------------------------------------------------------------
// xdbl (both streams): grid (NLT, BB, 4): z = str*2 + rev.
// ---------------------------------------------------------------------------
__global__ __launch_bounds__(256) void xdbl_kernel(
    const unsigned short* __restrict__ u, const unsigned short* __restrict__ xwbf,
    float* __restrict__ dtv_g, float* __restrict__ Bb, float* __restrict__ Cb) {
  __shared__ __align__(16) unsigned short ub[4][16][136];
  __shared__ float red[4][48][17];
  const int slab = blockIdx.z;
  const int b = blockIdx.y;
  const int lt = blockIdx.x;
  const int l0 = lt * 16;
  const int tid = threadIdx.x;
  const int lane = tid & 63;
  const int w = tid >> 6;
  const int rlo = lane & 15;
  const int hi4 = lane >> 4;
  const int kseg = hi4 * 8;

  const unsigned short* up = u + (size_t)slab * SZC + ((size_t)b * LL + l0) * DN;
  const unsigned short* xwb = xwbf + (size_t)slab * XWSL;
  float* B_out = Bb + (size_t)slab * NSZC;
  float* C_out = Cb + (size_t)slab * NSZC;

#pragma unroll
  for (int j = 0; j < 4; j++) {
    int idx = j * 256 + tid;
    int l2 = idx >> 6;
    int c8 = idx & 63;
    ushort8 v = *(const ushort8*)(up + (size_t)l2 * DN + c8 * 8);
    *(ushort8*)&ub[c8 >> 4][l2][(c8 & 15) * 8] = v;
  }
  __syncthreads();

  f32x4 am0 = (f32x4){0.f, 0.f, 0.f, 0.f};
  f32x4 am1 = (f32x4){0.f, 0.f, 0.f, 0.f};
  f32x4 am2 = (f32x4){0.f, 0.f, 0.f, 0.f};
#pragma unroll
  for (int ks = 0; ks < 4; ks++) {
    bf16x8 bfrag = *(bf16x8*)&ub[w][rlo][ks * 32 + kseg];
    const unsigned short* xp = xwb + (size_t)(w * 128 + ks * 32 + kseg);
    bf16x8 a0 = *(const bf16x8*)(xp + (size_t)(0 + rlo) * 512);
    bf16x8 a1 = *(const bf16x8*)(xp + (size_t)(16 + rlo) * 512);
    bf16x8 a2 = *(const bf16x8*)(xp + (size_t)(32 + rlo) * 512);
    am0 = __builtin_amdgcn_mfma_f32_16x16x32_bf16(a0, bfrag, am0, 0, 0, 0);
    am1 = __builtin_amdgcn_mfma_f32_16x16x32_bf16(a1, bfrag, am1, 0, 0, 0);
    am2 = __builtin_amdgcn_mfma_f32_16x16x32_bf16(a2, bfrag, am2, 0, 0, 0);
  }
  {
    const int rbase = hi4 * 4;
#pragma unroll
    for (int r = 0; r < 4; r++) red[w][0 + rbase + r][rlo] = am0[r];
#pragma unroll
    for (int r = 0; r < 4; r++) red[w][16 + rbase + r][rlo] = am1[r];
#pragma unroll
    for (int r = 0; r < 4; r++) red[w][32 + rbase + r][rlo] = am2[r];
  }
  __syncthreads();
  float* dtvp = dtv_g + (((size_t)slab * BB + b) * NLT + lt) * 256;
#pragma unroll
  for (int i = 0; i < 3; i++) {
    int o = i * 256 + tid;
    int row = o >> 4, col = o & 15;
    float s = (red[0][row][col] + red[1][row][col]) +
              (red[2][row][col] + red[3][row][col]);
    if (row < 16)
      dtvp[(size_t)row * 16 + col] = s;
    else if (row < 32)
      B_out[((size_t)b * LL + l0 + col) * NS + (row - 16)] = s;
    else
      C_out[((size_t)b * LL + l0 + col) * NS + (row - 32)] = s;
  }
}

// ---------------------------------------------------------------------------
// delta (both streams): dtv transposed in LDS; dl output BF16.
// ---------------------------------------------------------------------------
__global__ __launch_bounds__(256) void delta_kernel(
    const float* __restrict__ dtv_g,
    const float* __restrict__ dtw_af, const float* __restrict__ dtb_af,
    const float* __restrict__ dtw_ar, const float* __restrict__ dtb_ar,
    const float* __restrict__ dtw_vf, const float* __restrict__ dtb_vf,
    const float* __restrict__ dtw_vr, const float* __restrict__ dtb_vr,
    unsigned short* __restrict__ dl) {
  __shared__ __align__(16) float dtvT[16][20];
  const int slab = blockIdx.z;
  const int rev = slab & 1;
  const int str = slab >> 1;
  const int b = blockIdx.y;
  const int lt = blockIdx.x;
  const int l0 = lt * 16;
  const int tid = threadIdx.x;
  const float* dt_w = str ? (rev ? dtw_vr : dtw_vf) : (rev ? dtw_ar : dtw_af);
  const float* dt_b = str ? (rev ? dtb_vr : dtb_vf) : (rev ? dtb_ar : dtb_af);
  unsigned short* dl_out = dl + (size_t)slab * SZC;

  {
    const float* dtvp = dtv_g + (((size_t)slab * BB + b) * NLT + lt) * 256;
    float v = dtvp[tid];  // tid = k*16 + l
    dtvT[tid & 15][tid >> 4] = v;
  }
  __syncthreads();

  const int dd0 = tid, dd1 = tid + 256;
  const float4* wr0 = (const float4*)(dt_w + (size_t)dd0 * RK);
  const float4* wr1 = (const float4*)(dt_w + (size_t)dd1 * RK);
  float4 a_0 = wr0[0], a_1 = wr0[1], a_2 = wr0[2], a_3 = wr0[3];
  float4 b_0 = wr1[0], b_1 = wr1[1], b_2 = wr1[2], b_3 = wr1[3];
  float bias0 = dt_b[dd0], bias1 = dt_b[dd1];

#pragma unroll
  for (int l2 = 0; l2 < 16; l2++) {
    float4 q0 = *(const float4*)&dtvT[l2][0];
    float4 q1 = *(const float4*)&dtvT[l2][4];
    float4 q2 = *(const float4*)&dtvT[l2][8];
    float4 q3 = *(const float4*)&dtvT[l2][12];
    float s0 = bias0, s1 = bias1;
    s0 = fmaf(a_0.x, q0.x, s0); s1 = fmaf(b_0.x, q0.x, s1);
    s0 = fmaf(a_0.y, q0.y, s0); s1 = fmaf(b_0.y, q0.y, s1);
    s0 = fmaf(a_0.z, q0.z, s0); s1 = fmaf(b_0.z, q0.z, s1);
    s0 = fmaf(a_0.w, q0.w, s0); s1 = fmaf(b_0.w, q0.w, s1);
    s0 = fmaf(a_1.x, q1.x, s0); s1 = fmaf(b_1.x, q1.x, s1);
    s0 = fmaf(a_1.y, q1.y, s0); s1 = fmaf(b_1.y, q1.y, s1);
    s0 = fmaf(a_1.z, q1.z, s0); s1 = fmaf(b_1.z, q1.z, s1);
    s0 = fmaf(a_1.w, q1.w, s0); s1 = fmaf(b_1.w, q1.w, s1);
    s0 = fmaf(a_2.x, q2.x, s0); s1 = fmaf(b_2.x, q2.x, s1);
    s0 = fmaf(a_2.y, q2.y, s0); s1 = fmaf(b_2.y, q2.y, s1);
    s0 = fmaf(a_2.z, q2.z, s0); s1 = fmaf(b_2.z, q2.z, s1);
    s0 = fmaf(a_2.w, q2.w, s0); s1 = fmaf(b_2.w, q2.w, s1);
    s0 = fmaf(a_3.x, q3.x, s0); s1 = fmaf(b_3.x, q3.x, s1);
    s0 = fmaf(a_3.y, q3.y, s0); s1 = fmaf(b_3.y, q3.y, s1);
    s0 = fmaf(a_3.z, q3.z, s0); s1 = fmaf(b_3.z, q3.z, s1);
    s0 = fmaf(a_3.w, q3.w, s0); s1 = fmaf(b_3.w, q3.w, s1);
    unsigned short* rowp = dl_out + ((size_t)b * LL + l0 + l2) * DN;
    rowp[dd0] = f2bf(fsoftplus_fast(s0));
    rowp[dd1] = f2bf(fsoftplus_fast(s1));
  }
}

// ---------------------------------------------------------------------------
// Scan (both streams, LDS-staged; R25 config — proven optimum). z read
// DIRECT from global; u/dl staged; LDS 18.4 KB -> 8 blocks/CU; packed
// fast-A math (Av[n] = -(n+1) guarded).
// ---------------------------------------------------------------------------
template <int PHASE>
__global__ __launch_bounds__(256) void scan_kernel(
    unsigned short* __restrict__ u, const unsigned short* __restrict__ dl,
    const unsigned short* __restrict__ z_t, const float* __restrict__ Bb,
    const float* __restrict__ Cb, const float* __restrict__ A_log,
    const float* __restrict__ Ab_log,
    const float* __restrict__ D_af, const float* __restrict__ D_ar,
    const float* __restrict__ D_vf, const float* __restrict__ D_vr,
    unsigned short* __restrict__ hend, float* __restrict__ sumdl) {
  __shared__ unsigned short us[CL2][256];   // 8 KB
  __shared__ unsigned short dls[CL2][256];  // 8 KB
  __shared__ __align__(16) float Bs[CL2][16];
  __shared__ __align__(16) float Cs[CL2][16];
  const int tid = threadIdx.x;
  const int str = blockIdx.y;
  const int ch0 = (blockIdx.x & 15) * 256;
  const int chunk = blockIdx.x >> 4;
  const int ch = ch0 + tid;
  const bool rev = ch0 >= BB * DN;
  const int slab = str * 2 + (rev ? 1 : 0);
  const int cid0 = rev ? ch0 - BB * DN : ch0;
  const int b = cid0 >> 9;
  const int d0 = cid0 & (DN - 1);
  const int d = d0 + tid;

  const float* Arow = (rev ? Ab_log : A_log) + d * NS;
  float Av[NS];
#pragma unroll
  for (int n = 0; n < NS; n++) Av[n] = -__expf(Arow[n]);
  bool fastA = true;
#pragma unroll
  for (int n = 0; n < NS; n++)
    if (fabsf(Av[n] + (float)(n + 1)) > 1e-4f * (float)(n + 1)) fastA = false;
  const float* Dsel = str ? (rev ? D_vr : D_vf) : (rev ? D_ar : D_af);
  const float Dd = Dsel[d];

  const int tlo = rev ? (LL - CL2 * (chunk + 1)) : (CL2 * chunk);
  unsigned short* uyb = u + (size_t)slab * SZC + ((size_t)b * LL + tlo) * DN + d0;
  const unsigned short* dlb = dl + (size_t)slab * SZC + ((size_t)b * LL + tlo) * DN + d0;
  const unsigned short* zb = z_t + (size_t)str * SZC + ((size_t)b * LL + tlo) * DN + d0;
  const float* Bp = Bb + (size_t)slab * NSZC + ((size_t)b * LL + tlo) * NS;
  const float* Cp = Cb + (size_t)slab * NSZC + ((size_t)b * LL + tlo) * NS;
  unsigned short* hendp = hend + (size_t)str * HSZC;
  float* sumdlp = sumdl + (size_t)str * NC2 * G2C;

  // ---- stage u/dl chunk tiles (u aliases y -> must stage) ----
  {
    const int lane = tid & 63;
    const int w = tid >> 6;
#pragma unroll
    for (int j4 = 0; j4 < 4; j4++) {
      int row = w * 4 + j4;
      ushort4v uu = *(const ushort4v*)(uyb + (size_t)row * DN + lane * 4);
      *(ushort4v*)&us[row][lane * 4] = uu;
      ushort4v dd4 = *(const ushort4v*)(dlb + (size_t)row * DN + lane * 4);
      *(ushort4v*)&dls[row][lane * 4] = dd4;
    }
    Bs[tid >> 4][tid & 15] = Bp[(size_t)(tid >> 4) * NS + (tid & 15)];
    if (PHASE == 3) Cs[tid >> 4][tid & 15] = Cp[(size_t)(tid >> 4) * NS + (tid & 15)];
  }

  float h[NS];
  if (PHASE == 3) {
    const unsigned short* hp = hendp + ((size_t)chunk * G2C + ch) * NS;
#pragma unroll
    for (int n = 0; n < NS; n++) h[n] = bf2f(hp[n]);
  } else {
#pragma unroll
    for (int n = 0; n < NS; n++) h[n] = 0.f;
  }
  __syncthreads();

  float sdl = 0.f;
  if (fastA) {
    f32x2 h2[8];
#pragma unroll
    for (int k = 0; k < 8; k++) h2[k] = (f32x2){h[2 * k], h[2 * k + 1]};
#pragma unroll
    for (int jj = 0; jj < CL2; jj++) {
      const int j = rev ? (CL2 - 1 - jj) : jj;
      const float uc = bf2f(us[j][tid]);
      const float dc = bf2f(dls[j][tid]);
      const f32x2* B2 = (const f32x2*)&Bs[j][0];
      const f32x2* C2 = (const f32x2*)&Cs[j][0];
      const float dlu = dc * uc;
      const f32x2 dlu2 = (f32x2){dlu, dlu};
      const float p1 = __expf(-dc);
      const float p2 = p1 * p1;
      const f32x2 p22 = (f32x2){p2, p2};
      f32x2 P[8];
      P[0] = (f32x2){p1, p2};
#pragma unroll
      for (int k = 1; k < 8; k++) P[k] = P[k - 1] * p22;
      f32x2 acc2 = (f32x2){0.f, 0.f};
#pragma unroll
      for (int k = 0; k < 8; k++) {
        f32x2 db2 = dlu2 * B2[k];
        h2[k] = __builtin_elementwise_fma(P[k], h2[k], db2);
        if (PHASE == 3) acc2 = __builtin_elementwise_fma(h2[k], C2[k], acc2);
      }
      if (PHASE == 1) sdl += dc;
      if (PHASE == 3) {
        const float zc = bf2f(zb[(size_t)j * DN + tid]);  // direct global read
        float y = fmaf(uc, Dd, acc2.x + acc2.y) * zc;
        uyb[(size_t)j * DN + tid] = f2bf(y);
      }
    }
#pragma unroll
    for (int k = 0; k < 8; k++) { h[2 * k] = h2[k].x; h[2 * k + 1] = h2[k].y; }
  } else {
#pragma unroll
    for (int jj = 0; jj < CL2; jj++) {
      const int j = rev ? (CL2 - 1 - jj) : jj;
      const float uc = bf2f(us[j][tid]);
      const float dc = bf2f(dls[j][tid]);
      const float dlu = dc * uc;
      float acc = 0.f;
#pragma unroll
      for (int n = 0; n < NS; n++) {
        h[n] = fmaf(__expf(dc * Av[n]), h[n], dlu * Bs[j][n]);
        if (PHASE == 3) acc = fmaf(h[n], Cs[j][n], acc);
      }
      if (PHASE == 1) sdl += dc;
      if (PHASE == 3) {
        const float zc = bf2f(zb[(size_t)j * DN + tid]);
        float y = fmaf(uc, Dd, acc) * zc;
        uyb[(size_t)j * DN + tid] = f2bf(y);
      }
    }
  }
  if (PHASE == 1) {
    unsigned short* hp = hendp + ((size_t)chunk * G2C + ch) * NS;
#pragma unroll
    for (int n = 0; n < NS; n++) hp[n] = f2bf(h[n]);
    sumdlp[(size_t)chunk * G2C + ch] = sdl;
  }
}

// ---------------------------------------------------------------------------
// Phase 2 (both streams): grid (G2C/16, 2).
// ---------------------------------------------------------------------------
__global__ __launch_bounds__(256) void scan_combine_kernel(
    const float* __restrict__ A_log, const float* __restrict__ Ab_log,
    unsigned short* __restrict__ hend, const float* __restrict__ sumdl) {
  __shared__ float tile[8][256];
  __shared__ float sd[8][16];
  const int tid = threadIdx.x;
  const int str = blockIdx.y;
  const int ch0 = blockIdx.x * 16;
  const int chl = tid >> 4;
  const int n = tid & 15;
  const int ch = ch0 + chl;
  const bool rev = ch >= BB * DN;
  const int d = ch & (DN - 1);
  const float Av = -__expf((rev ? Ab_log : A_log)[d * NS + n]);
  unsigned short* hendp = hend + (size_t)str * HSZC;
  const float* sumdlp = sumdl + (size_t)str * NC2 * G2C;
  float H = 0.f;
  for (int cb = 0; cb < NC2 / 8; cb++) {
#pragma unroll
    for (int j = 0; j < 8; j++)
      tile[j][tid] = bf2f(hendp[((size_t)(cb * 8 + j) * G2C + ch0) * NS + tid]);
    if (tid < 128) {
      int j = tid >> 4, k = tid & 15;
      sd[j][k] = sumdlp[(size_t)(cb * 8 + j) * G2C + ch0 + k];
    }
    __syncthreads();
#pragma unroll
    for (int j = 0; j < 8; j++) {
      float tmp = tile[j][tid];
      tile[j][tid] = H;
      H = fmaf(__expf(Av * sd[j][chl]), H, tmp);
    }
    __syncthreads();
#pragma unroll
    for (int j = 0; j < 8; j++)
      hendp[((size_t)(cb * 8 + j) * G2C + ch0) * NS + tid] = f2bf(tile[j][tid]);
    __syncthreads();
  }
}

// ---------------------------------------------------------------------------
// out_proj (both streams): grid (32, 4, BB*2).
// ---------------------------------------------------------------------------
__global__ __launch_bounds__(256) void out_proj_mfma(
    const unsigned short* __restrict__ u,
    const float* __restrict__ ow_a, const float* __restrict__ ow_v,
    float* __restrict__ outp) {
  __shared__ unsigned short yt[64][40];
  __shared__ unsigned short wo[64][40];
  const int bz = blockIdx.z;
  const int b = bz & 3;
  const int str = bz >> 2;
  const float* ow = str ? ow_v : ow_a;
  const unsigned short* yf = u + (size_t)(str * 2) * SZC;
  const unsigned short* yr = u + (size_t)(str * 2 + 1) * SZC;
  float* outs = outp + (size_t)str * BB * LL * DM;
  const int m0 = blockIdx.y * 64;
  const int l0 = blockIdx.x * 64;
  const int tid = threadIdx.x;
  const int lane = tid & 63;
  const int wid = tid >> 6;
  const int wm = wid >> 1, wn = wid & 1;
  const int krow = (lane >> 4) * 8;
  const int rlo = lane & 15;

  f32x4 acc[2][2];
#pragma unroll
  for (int i = 0; i < 2; i++)
#pragma unroll
    for (int j = 0; j < 2; j++) acc[i][j] = (f32x4){0.f, 0.f, 0.f, 0.f};

  for (int dk = 0; dk < DN; dk += 32) {
    {
      int row = tid >> 2;
      int seg = (tid & 3) * 8;
      ushort8 a = *(const ushort8*)(yf + ((size_t)b * LL + l0 + row) * DN + dk + seg);
      ushort8 c = *(const ushort8*)(yr + ((size_t)b * LL + l0 + row) * DN + dk + seg);
      ushort8 yv;
#pragma unroll
      for (int k = 0; k < 8; k++) yv[k] = f2bf(0.5f * (bf2f(a[k]) + bf2f(c[k])));
      *(ushort8*)&yt[row][seg] = yv;
      const float* wp = ow + (size_t)(m0 + row) * DN + dk + seg;
      float4 w0 = *(const float4*)wp, w1 = *(const float4*)(wp + 4);
      ushort8 wv;
      wv[0] = f2bf(w0.x); wv[1] = f2bf(w0.y); wv[2] = f2bf(w0.z); wv[3] = f2bf(w0.w);
      wv[4] = f2bf(w1.x); wv[5] = f2bf(w1.y); wv[6] = f2bf(w1.z); wv[7] = f2bf(w1.w);
      *(ushort8*)&wo[row][seg] = wv;
    }
    __syncthreads();
    bf16x8 a0 = *(bf16x8*)&yt[wm * 32 + rlo][krow];
    bf16x8 a1 = *(bf16x8*)&yt[wm * 32 + 16 + rlo][krow];
    bf16x8 b0 = *(bf16x8*)&wo[wn * 32 + rlo][krow];
    bf16x8 b1 = *(bf16x8*)&wo[wn * 32 + 16 + rlo][krow];
    acc[0][0] = __builtin_amdgcn_mfma_f32_16x16x32_bf16(a0, b0, acc[0][0], 0, 0, 0);
    acc[0][1] = __builtin_amdgcn_mfma_f32_16x16x32_bf16(a0, b1, acc[0][1], 0, 0, 0);
    acc[1][0] = __builtin_amdgcn_mfma_f32_16x16x32_bf16(a1, b0, acc[1][0], 0, 0, 0);
    acc[1][1] = __builtin_amdgcn_mfma_f32_16x16x32_bf16(a1, b1, acc[1][1], 0, 0, 0);
    __syncthreads();
  }
#pragma unroll
  for (int mt = 0; mt < 2; mt++)
#pragma unroll
    for (int nt = 0; nt < 2; nt++)
#pragma unroll
      for (int r = 0; r < 4; r++) {
        int l = l0 + wm * 32 + mt * 16 + (lane >> 4) * 4 + r;
        int m = m0 + wn * 32 + nt * 16 + rlo;
        outs[((size_t)b * LL + l) * DM + m] = acc[mt][nt][r];
      }
}

// ---------------------------------------------------------------------------
extern "C" void kernel_launch(void* const* d_in, const int* in_sizes, int n_in,
                              void* d_out, int out_size, void* d_ws, size_t ws_size,
                              hipStream_t stream) {
  (void)in_sizes; (void)n_in; (void)out_size; (void)ws_size;
  const float* A_log = (const float*)d_in[2];
  const float* Ab_log = (const float*)d_in[3];
  const float* h_a = (const float*)d_in[0];
  const float* h_v = (const float*)d_in[1];
#define AP(i) ((const float*)d_in[4 + (i)])
#define VP(i) ((const float*)d_in[18 + (i)])

  float* ws = (float*)d_ws;
  float* Bb = ws;                                   // 4*NSZC fp32
  float* Cb = Bb + 4 * NSZC;                        // 4*NSZC
  float* sumdl = Cb + 4 * NSZC;                     // 2*NC2*G2C
  float* dtv_g = sumdl + (size_t)2 * NC2 * G2C;     // 4*BB*NLT*256
  unsigned short* xwbf = (unsigned short*)(dtv_g + (size_t)4 * BB * NLT * 256);
  unsigned short* z_t = xwbf + 4 * XWSL;            // 2*SZC bf16
  unsigned short* u = z_t + 2 * SZC;                // 4*SZC bf16
  unsigned short* xz = u + 4 * SZC;                 // 2*SZC bf16
  unsigned short* hend = xz + 2 * SZC;              // 2*HSZC bf16
  unsigned short* dl = hend + 2 * HSZC;             // 4*SZC bf16

  hipLaunchKernelGGL(in_proj_mfma, dim3(LL / 64, EE / 128, BB * 2), dim3(256), 0,
                     stream, h_a, h_v, AP(0), VP(0), xz, z_t);
  hipLaunchKernelGGL(xw_prep_kernel, dim3(96), dim3(256), 0, stream,
                     AP(3), AP(9), VP(3), VP(9), xwbf);
  hipLaunchKernelGGL(conv_kernel, dim3((LL / 32) * 4, BB, 4), dim3(256), 0, stream,
                     xz, AP(1), AP(2), AP(7), AP(8), VP(1), VP(2), VP(7), VP(8), u);
  hipLaunchKernelGGL(xdbl_kernel, dim3(NLT, BB, 4), dim3(256), 0, stream,
                     u, xwbf, dtv_g, Bb, Cb);
  hipLaunchKernelGGL(delta_kernel, dim3(NLT, BB, 4), dim3(256), 0, stream,
                     dtv_g, AP(4), AP(5), AP(10), AP(11), VP(4), VP(5), VP(10),
                     VP(11), dl);
  hipLaunchKernelGGL(HIP_KERNEL_NAME(scan_kernel<1>), dim3(NC2 * 16, 2), dim3(256),
                     0, stream, u, dl, z_t, Bb, Cb, A_log, Ab_log, AP(6), AP(12),
                     VP(6), VP(12), hend, sumdl);
  hipLaunchKernelGGL(scan_combine_kernel, dim3(G2C / 16, 2), dim3(256), 0, stream,
                     A_log, Ab_log, hend, sumdl);
  hipLaunchKernelGGL(HIP_KERNEL_NAME(scan_kernel<3>), dim3(NC2 * 16, 2), dim3(256),
                     0, stream, u, dl, z_t, Bb, Cb, A_log, Ab_log, AP(6), AP(12),
                     VP(6), VP(12), hend, sumdl);
  hipLaunchKernelGGL(out_proj_mfma, dim3(LL / 64, DM / 64, BB * 2), dim3(256), 0,
                     stream, u, AP(13), VP(13), (float*)d_out);
#undef AP
#undef VP
}